// Round 2
// baseline (578.471 us; speedup 1.0000x reference)
//
#include <hip/hip_runtime.h>
#include <hip/hip_bf16.h>

typedef unsigned short u16;
typedef unsigned int u32;
typedef __attribute__((ext_vector_type(8))) short short8;
typedef __attribute__((ext_vector_type(8))) unsigned short ushort8;
typedef __attribute__((ext_vector_type(4))) float f32x4;

#define AS1 __attribute__((address_space(1)))
#define AS3 __attribute__((address_space(3)))

#define Bb_ 128
#define Nn_ 512
#define Cc_ 512
#define NK_ 515

__device__ __forceinline__ u16 f2bf(float f) {
    union { float f; u32 i; } t; t.f = f;
    u32 x = t.i;
    u32 r = (x + 0x7fffu + ((x >> 16) & 1u)) >> 16;  // round-nearest-even
    return (u16)r;
}

// ---------------------------------------------------------------------------
// Kernel 1 (fused prep): per (b,n) row of fp32 query:
//   qbf[row][c] = bf16(q[row][c])           (row-contiguous, 16B stores)
//   dw[row][j]  = sum_c q[row][c]*W[c][j] + b_lin[j]   (fp32, j=0..2)
// One wave per row, 4 waves/block.
// ---------------------------------------------------------------------------
__global__ void prep_kernel(const float* __restrict__ q, const float* __restrict__ W,
                            const float* __restrict__ bl,
                            u16* __restrict__ qbf, float* __restrict__ dw) {
    __shared__ float wc[3][512];
    int tid = threadIdx.x;
    for (int idx = tid; idx < 3 * 512; idx += 256) {
        int j = idx >> 9, c = idx & 511;
        wc[j][c] = W[c * NK_ + j];
    }
    __syncthreads();

    int w = tid >> 6, l = tid & 63;
    size_t row = (size_t)blockIdx.x * 4 + w;   // 0 .. B*N-1
    const float* qr = q + row * Cc_;
    u16* qb = qbf + row * Cc_;
    float s0 = 0.f, s1 = 0.f, s2 = 0.f;
    int c0 = l * 8;
    f32x4 x0 = *(const f32x4*)(qr + c0);
    f32x4 x1 = *(const f32x4*)(qr + c0 + 4);
    float xf[8] = {x0[0], x0[1], x0[2], x0[3], x1[0], x1[1], x1[2], x1[3]};
    ushort8 y;
#pragma unroll
    for (int e = 0; e < 8; e++) {
        int c = c0 + e;
        float qf = xf[e];
        y[e] = f2bf(qf);
        s0 += qf * wc[0][c];
        s1 += qf * wc[1][c];
        s2 += qf * wc[2][c];
    }
    *(ushort8*)(qb + c0) = y;
#pragma unroll
    for (int off = 32; off > 0; off >>= 1) {
        s0 += __shfl_xor(s0, off);
        s1 += __shfl_xor(s1, off);
        s2 += __shfl_xor(s2, off);
    }
    if (l == 0) {
        dw[row * 3 + 0] = s0 + bl[0];
        dw[row * 3 + 1] = s1 + bl[1];
        dw[row * 3 + 2] = s2 + bl[2];
    }
}

// ---------------------------------------------------------------------------
// Kernel 2: WT[n][c] = bf16(W_lin[c][n+3])   (512x512)
// ---------------------------------------------------------------------------
__global__ void wt_kernel(const float* __restrict__ W, u16* __restrict__ WT) {
    int n = blockIdx.y;
    int c = blockIdx.x * 256 + threadIdx.x;
    WT[n * Cc_ + c] = f2bf(W[c * NK_ + n + 3]);
}

// ---------------------------------------------------------------------------
// Kernel 3: depthT[b][c][n] = bf16(relu(dw0*v[c-1] + dw1*v[c] + dw2*v[c+1]))
// 64x64 tile per block with LDS transpose. blockIdx: x=c-tile, y=n-tile, z=b
// ---------------------------------------------------------------------------
__global__ void depthT_kernel(const float* __restrict__ val, const float* __restrict__ dw,
                              u16* __restrict__ dT) {
    __shared__ float vt[64][67];   // stride 67: conflict-free column reads
    __shared__ float dws[64][3];
    int b = blockIdx.z;
    int c0 = blockIdx.x * 64;
    int n0 = blockIdx.y * 64;
    int tid = threadIdx.x;

    const float* vbase = val + ((size_t)b * Nn_ + n0) * Cc_;
    for (int idx = tid; idx < 64 * 66; idx += 256) {
        int r = idx / 66, cc = idx % 66;
        int c = c0 - 1 + cc;
        float x = 0.f;
        if (c >= 0 && c < Cc_) x = vbase[(size_t)r * Cc_ + c];
        vt[r][cc] = x;
    }
    if (tid < 192) {
        int r = tid / 3, j = tid % 3;
        dws[r][j] = dw[((size_t)b * Nn_ + n0 + r) * 3 + j];
    }
    __syncthreads();

    int nn = tid & 63;
    int ccb = tid >> 6;   // 0..3
    u16* out = dT + ((size_t)b * Cc_ + c0) * Nn_ + n0;
    float d0 = dws[nn][0], d1 = dws[nn][1], d2 = dws[nn][2];
#pragma unroll
    for (int p = 0; p < 16; p++) {
        int cc = ccb + p * 4;
        float x = d0 * vt[nn][cc] + d1 * vt[nn][cc + 1] + d2 * vt[nn][cc + 2];
        x = x > 0.f ? x : 0.f;
        out[(size_t)cc * Nn_ + nn] = f2bf(x);
    }
}

// ---------------------------------------------------------------------------
// Kernel 4: batched NT GEMM: Out[b][m][n] = sum_k A[b][m][k]*Bt[b][n][k] (+bias[n])
// M=N=K=512, bf16 inputs, fp32 accum. 128x128 tile, BK=32, 4 waves of 64x64
// (4x4 mfma 16x16x32 bf16). global_load_lds width-16 staging (m97 structure).
// F32OUT: write fp32, else bf16.
// ---------------------------------------------------------------------------
template <int BIAS, int F32OUT>
__global__ __launch_bounds__(256, 2) void gemm_bt(const u16* __restrict__ A,
                                                  const u16* __restrict__ Bt,
                                                  void* __restrict__ Outv,
                                                  const float* __restrict__ bias,
                                                  long sA, long sB, long sO) {
    __shared__ __align__(16) u16 lA[128 * 32];
    __shared__ __align__(16) u16 lB[128 * 32];

    int b = blockIdx.y;
    int tileM = blockIdx.x >> 2;
    int tileN = blockIdx.x & 3;
    const u16* Ab = A + (size_t)b * sA + (size_t)tileM * 128 * 512;
    const u16* Bbp = Bt + (size_t)b * sB + (size_t)tileN * 128 * 512;

    int tid = threadIdx.x, w = tid >> 6, l = tid & 63;
    int rsub = l >> 2;      // 0..15: row within 16-row segment
    int csub = l & 3;       // 0..3 : 16B chunk within 64B row
    int wm = w & 1, wn = w >> 1;
    int m_off = wm * 64, n_off = wn * 64;
    int row_l = l & 15, quad = l >> 4;

    f32x4 acc[4][4];
#pragma unroll
    for (int i = 0; i < 4; i++)
#pragma unroll
        for (int j = 0; j < 4; j++) acc[i][j] = (f32x4){0.f, 0.f, 0.f, 0.f};

    for (int kt = 0; kt < 16; kt++) {
        __syncthreads();
        int kof = kt * 32;
#pragma unroll
        for (int j = 0; j < 2; j++) {
            int seg = w * 2 + j;            // 0..7
            int r = seg * 16 + rsub;        // 0..127
            const u16* gA = Ab + (size_t)r * 512 + kof + csub * 8;
            __builtin_amdgcn_global_load_lds((const AS1 u32*)gA,
                                             (AS3 u32*)&lA[seg * 512], 16, 0, 0);
            const u16* gB = Bbp + (size_t)r * 512 + kof + csub * 8;
            __builtin_amdgcn_global_load_lds((const AS1 u32*)gB,
                                             (AS3 u32*)&lB[seg * 512], 16, 0, 0);
        }
        __syncthreads();

        short8 aF[4], bF[4];
#pragma unroll
        for (int i = 0; i < 4; i++)
            aF[i] = *(const short8*)&lA[(m_off + i * 16 + row_l) * 32 + quad * 8];
#pragma unroll
        for (int j = 0; j < 4; j++)
            bF[j] = *(const short8*)&lB[(n_off + j * 16 + row_l) * 32 + quad * 8];

#pragma unroll
        for (int i = 0; i < 4; i++)
#pragma unroll
            for (int j = 0; j < 4; j++)
                acc[i][j] = __builtin_amdgcn_mfma_f32_16x16x32_bf16(aF[i], bF[j], acc[i][j], 0, 0, 0);
    }

#pragma unroll
    for (int i = 0; i < 4; i++) {
#pragma unroll
        for (int j = 0; j < 4; j++) {
            int gn = n_off + j * 16 + row_l;
            float bv = 0.f;
            if (BIAS) bv = bias[tileN * 128 + gn];
#pragma unroll
            for (int r = 0; r < 4; r++) {
                int gm = m_off + i * 16 + quad * 4 + r;
                float vv = acc[i][j][r] + bv;
                size_t idx = (size_t)b * sO + (size_t)tileM * 128 * 512 + tileN * 128 +
                             (size_t)gm * 512 + gn;
                if (F32OUT) ((float*)Outv)[idx] = vv;
                else        ((u16*)Outv)[idx] = f2bf(vv);
            }
        }
    }
}

// ---------------------------------------------------------------------------
// Kernel 5: in-place fp32 LayerNorm over C=512, one wave per row.
// ---------------------------------------------------------------------------
__global__ void ln_kernel(float* __restrict__ out, const float* __restrict__ gamma,
                          const float* __restrict__ beta) {
    int tid = threadIdx.x, w = tid >> 6, l = tid & 63;
    size_t row = (size_t)blockIdx.x * 4 + w;
    float* p = out + row * Cc_ + l * 8;
    f32x4 x0 = *(const f32x4*)p;
    f32x4 x1 = *(const f32x4*)(p + 4);
    float xf[8] = {x0[0], x0[1], x0[2], x0[3], x1[0], x1[1], x1[2], x1[3]};
    float s = 0.f, ss = 0.f;
#pragma unroll
    for (int e = 0; e < 8; e++) {
        s += xf[e];
        ss += xf[e] * xf[e];
    }
#pragma unroll
    for (int off = 32; off > 0; off >>= 1) {
        s += __shfl_xor(s, off);
        ss += __shfl_xor(ss, off);
    }
    float mu = s * (1.f / 512.f);
    float var = ss * (1.f / 512.f) - mu * mu;
    float rs = rsqrtf(var + 1e-5f);
    f32x4 g0 = *(const f32x4*)(gamma + l * 8);
    f32x4 g1 = *(const f32x4*)(gamma + l * 8 + 4);
    f32x4 b0 = *(const f32x4*)(beta + l * 8);
    f32x4 b1 = *(const f32x4*)(beta + l * 8 + 4);
    float gf[8] = {g0[0], g0[1], g0[2], g0[3], g1[0], g1[1], g1[2], g1[3]};
    float bf[8] = {b0[0], b0[1], b0[2], b0[3], b1[0], b1[1], b1[2], b1[3]};
    f32x4 y0, y1;
#pragma unroll
    for (int e = 0; e < 8; e++) {
        float v = (xf[e] - mu) * rs * gf[e] + bf[e];
        if (e < 4) y0[e] = v; else y1[e - 4] = v;
    }
    *(f32x4*)p = y0;
    *(f32x4*)(p + 4) = y1;
}

// ---------------------------------------------------------------------------
extern "C" void kernel_launch(void* const* d_in, const int* in_sizes, int n_in,
                              void* d_out, int out_size, void* d_ws, size_t ws_size,
                              hipStream_t stream) {
    const float* q     = (const float*)d_in[0];
    const float* v     = (const float*)d_in[1];
    const float* W     = (const float*)d_in[2];
    const float* bl    = (const float*)d_in[3];
    const float* gamma = (const float*)d_in[4];
    const float* beta  = (const float*)d_in[5];

    char* ws = (char*)d_ws;
    u16*   WT  = (u16*)ws;                                 // 512*512*2      = 524288
    float* dw  = (float*)(ws + 524288);                    // 128*512*3*4    = 786432
    u16*   pw  = (u16*)(ws + 1310720);                     // 128*512*512*2  = 67108864
    u16*   dT  = (u16*)(ws + 68419584);                    // 128*512*512*2  = 67108864
    float* out = (float*)d_out;
    u16*   qbf = (u16*)d_out;   // first 67 MB of d_out as scratch; dead before GEMM2 writes

    prep_kernel<<<dim3((Bb_ * Nn_) / 4), 256, 0, stream>>>(q, W, bl, qbf, dw);
    wt_kernel<<<dim3(2, 512), 256, 0, stream>>>(W, WT);
    depthT_kernel<<<dim3(8, 8, Bb_), 256, 0, stream>>>(v, dw, dT);

    // GEMM1: pw[b][m][n] = sum_c qbf[b][m][c] * WT[n][c] + b_lin[n+3]   (bf16 out)
    gemm_bt<1, 0><<<dim3(16, Bb_), 256, 0, stream>>>(qbf, WT, pw, bl + 3,
                                                     (long)Nn_ * Cc_, 0L, (long)Nn_ * Nn_);
    // GEMM2: out[b][m][c] = sum_n pw[b][m][n] * depthT[b][c][n]         (fp32 out)
    gemm_bt<0, 1><<<dim3(16, Bb_), 256, 0, stream>>>(pw, dT, out, nullptr,
                                                     (long)Nn_ * Nn_, (long)Cc_ * Nn_, (long)Nn_ * Cc_);

    ln_kernel<<<dim3((Bb_ * Nn_) / 4), 256, 0, stream>>>(out, gamma, beta);
}

// Round 3
// 547.485 us; speedup vs baseline: 1.0566x; 1.0566x over previous
//
#include <hip/hip_runtime.h>
#include <hip/hip_bf16.h>

typedef unsigned short u16;
typedef unsigned int u32;
typedef __attribute__((ext_vector_type(8))) short short8;
typedef __attribute__((ext_vector_type(8))) unsigned short ushort8;
typedef __attribute__((ext_vector_type(4))) float f32x4;

#define AS1 __attribute__((address_space(1)))
#define AS3 __attribute__((address_space(3)))

#define Bb_ 128
#define Nn_ 512
#define Cc_ 512
#define NK_ 515

__device__ __forceinline__ u16 f2bf(float f) {
    union { float f; u32 i; } t; t.f = f;
    u32 x = t.i;
    u32 r = (x + 0x7fffu + ((x >> 16) & 1u)) >> 16;  // round-nearest-even
    return (u16)r;
}

// ---------------------------------------------------------------------------
// Kernel 1 (fused prep, v2): per (b,n) row of fp32 query:
//   qbf[row][c] = bf16(q[row][c])
//   dw[row][j]  = sum_c q[row][c]*W[c][j] + b_lin[j]   (fp32, j=0..2)
// One wave per 32 rows; per-lane conv weights hoisted to registers (the v1
// version re-read them from LDS per element -> 8-way bank conflict, 105 us).
// ---------------------------------------------------------------------------
#define ROWS_PER_WAVE 32
__global__ void prep_kernel(const float* __restrict__ q, const float* __restrict__ W,
                            const float* __restrict__ bl,
                            u16* __restrict__ qbf, float* __restrict__ dw) {
    __shared__ float wc[3][512];
    int tid = threadIdx.x;
    for (int idx = tid; idx < 3 * 512; idx += 256) {
        int j = idx >> 9, c = idx & 511;
        wc[j][c] = W[c * NK_ + j];
    }
    __syncthreads();

    int w = tid >> 6, l = tid & 63;
    int c0 = l * 8;
    float w0[8], w1[8], w2[8];
#pragma unroll
    for (int e = 0; e < 8; e++) {
        w0[e] = wc[0][c0 + e];
        w1[e] = wc[1][c0 + e];
        w2[e] = wc[2][c0 + e];
    }
    float bl0 = bl[0], bl1 = bl[1], bl2 = bl[2];

    size_t row0 = (size_t)blockIdx.x * (4 * ROWS_PER_WAVE) + (size_t)w * ROWS_PER_WAVE;
#pragma unroll 2
    for (int rr = 0; rr < ROWS_PER_WAVE; rr++) {
        size_t row = row0 + rr;
        const float* qr = q + row * Cc_;
        f32x4 x0 = *(const f32x4*)(qr + c0);
        f32x4 x1 = *(const f32x4*)(qr + c0 + 4);
        float xf[8] = {x0[0], x0[1], x0[2], x0[3], x1[0], x1[1], x1[2], x1[3]};
        ushort8 y;
        float s0 = 0.f, s1 = 0.f, s2 = 0.f;
#pragma unroll
        for (int e = 0; e < 8; e++) {
            float qf = xf[e];
            y[e] = f2bf(qf);
            s0 += qf * w0[e];
            s1 += qf * w1[e];
            s2 += qf * w2[e];
        }
        *(ushort8*)(qbf + row * Cc_ + c0) = y;
#pragma unroll
        for (int off = 32; off > 0; off >>= 1) {
            s0 += __shfl_xor(s0, off);
            s1 += __shfl_xor(s1, off);
            s2 += __shfl_xor(s2, off);
        }
        if (l == 0) {
            dw[row * 3 + 0] = s0 + bl0;
            dw[row * 3 + 1] = s1 + bl1;
            dw[row * 3 + 2] = s2 + bl2;
        }
    }
}

// ---------------------------------------------------------------------------
// Kernel 2: WT[n][c] = bf16(W_lin[c][n+3])   (512x512)
// ---------------------------------------------------------------------------
__global__ void wt_kernel(const float* __restrict__ W, u16* __restrict__ WT) {
    int n = blockIdx.y;
    int c = blockIdx.x * 256 + threadIdx.x;
    WT[n * Cc_ + c] = f2bf(W[c * NK_ + n + 3]);
}

// ---------------------------------------------------------------------------
// Kernel 3: depthT[b][c][n] = bf16(relu(dw0*v[c-1] + dw1*v[c] + dw2*v[c+1]))
// 64x64 tile per block with LDS transpose. blockIdx: x=c-tile, y=n-tile, z=b
// ---------------------------------------------------------------------------
__global__ void depthT_kernel(const float* __restrict__ val, const float* __restrict__ dw,
                              u16* __restrict__ dT) {
    __shared__ float vt[64][67];   // stride 67: conflict-free column reads
    __shared__ float dws[64][3];
    int b = blockIdx.z;
    int c0 = blockIdx.x * 64;
    int n0 = blockIdx.y * 64;
    int tid = threadIdx.x;

    const float* vbase = val + ((size_t)b * Nn_ + n0) * Cc_;
    for (int idx = tid; idx < 64 * 66; idx += 256) {
        int r = idx / 66, cc = idx % 66;
        int c = c0 - 1 + cc;
        float x = 0.f;
        if (c >= 0 && c < Cc_) x = vbase[(size_t)r * Cc_ + c];
        vt[r][cc] = x;
    }
    if (tid < 192) {
        int r = tid / 3, j = tid % 3;
        dws[r][j] = dw[((size_t)b * Nn_ + n0 + r) * 3 + j];
    }
    __syncthreads();

    int nn = tid & 63;
    int ccb = tid >> 6;   // 0..3
    u16* out = dT + ((size_t)b * Cc_ + c0) * Nn_ + n0;
    float d0 = dws[nn][0], d1 = dws[nn][1], d2 = dws[nn][2];
#pragma unroll
    for (int p = 0; p < 16; p++) {
        int cc = ccb + p * 4;
        float x = d0 * vt[nn][cc] + d1 * vt[nn][cc + 1] + d2 * vt[nn][cc + 2];
        x = x > 0.f ? x : 0.f;
        out[(size_t)cc * Nn_ + nn] = f2bf(x);
    }
}

// ---------------------------------------------------------------------------
// Kernel 4: batched NT GEMM: Out[b][m][n] = sum_k A[b][m][k]*Bt[b][n][k] (+bias[n])
// M=N=K=512, bf16 inputs, fp32 accum. 128x128 tile, BK=32, 4 waves of 64x64
// (4x4 mfma 16x16x32 bf16). global_load_lds width-16 staging (m97 structure).
// F32OUT: write fp32, else bf16.
// ---------------------------------------------------------------------------
template <int BIAS, int F32OUT>
__global__ __launch_bounds__(256, 2) void gemm_bt(const u16* __restrict__ A,
                                                  const u16* __restrict__ Bt,
                                                  void* __restrict__ Outv,
                                                  const float* __restrict__ bias,
                                                  long sA, long sB, long sO) {
    __shared__ __align__(16) u16 lA[128 * 32];
    __shared__ __align__(16) u16 lB[128 * 32];

    int b = blockIdx.y;
    int tileM = blockIdx.x >> 2;
    int tileN = blockIdx.x & 3;
    const u16* Ab = A + (size_t)b * sA + (size_t)tileM * 128 * 512;
    const u16* Bbp = Bt + (size_t)b * sB + (size_t)tileN * 128 * 512;

    int tid = threadIdx.x, w = tid >> 6, l = tid & 63;
    int rsub = l >> 2;      // 0..15: row within 16-row segment
    int csub = l & 3;       // 0..3 : 16B chunk within 64B row
    int wm = w & 1, wn = w >> 1;
    int m_off = wm * 64, n_off = wn * 64;
    int row_l = l & 15, quad = l >> 4;

    f32x4 acc[4][4];
#pragma unroll
    for (int i = 0; i < 4; i++)
#pragma unroll
        for (int j = 0; j < 4; j++) acc[i][j] = (f32x4){0.f, 0.f, 0.f, 0.f};

    for (int kt = 0; kt < 16; kt++) {
        __syncthreads();
        int kof = kt * 32;
#pragma unroll
        for (int j = 0; j < 2; j++) {
            int seg = w * 2 + j;            // 0..7
            int r = seg * 16 + rsub;        // 0..127
            const u16* gA = Ab + (size_t)r * 512 + kof + csub * 8;
            __builtin_amdgcn_global_load_lds((const AS1 u32*)gA,
                                             (AS3 u32*)&lA[seg * 512], 16, 0, 0);
            const u16* gB = Bbp + (size_t)r * 512 + kof + csub * 8;
            __builtin_amdgcn_global_load_lds((const AS1 u32*)gB,
                                             (AS3 u32*)&lB[seg * 512], 16, 0, 0);
        }
        __syncthreads();

        short8 aF[4], bF[4];
#pragma unroll
        for (int i = 0; i < 4; i++)
            aF[i] = *(const short8*)&lA[(m_off + i * 16 + row_l) * 32 + quad * 8];
#pragma unroll
        for (int j = 0; j < 4; j++)
            bF[j] = *(const short8*)&lB[(n_off + j * 16 + row_l) * 32 + quad * 8];

#pragma unroll
        for (int i = 0; i < 4; i++)
#pragma unroll
            for (int j = 0; j < 4; j++)
                acc[i][j] = __builtin_amdgcn_mfma_f32_16x16x32_bf16(aF[i], bF[j], acc[i][j], 0, 0, 0);
    }

#pragma unroll
    for (int i = 0; i < 4; i++) {
#pragma unroll
        for (int j = 0; j < 4; j++) {
            int gn = n_off + j * 16 + row_l;
            float bv = 0.f;
            if (BIAS) bv = bias[tileN * 128 + gn];
#pragma unroll
            for (int r = 0; r < 4; r++) {
                int gm = m_off + i * 16 + quad * 4 + r;
                float vv = acc[i][j][r] + bv;
                size_t idx = (size_t)b * sO + (size_t)tileM * 128 * 512 + tileN * 128 +
                             (size_t)gm * 512 + gn;
                if (F32OUT) ((float*)Outv)[idx] = vv;
                else        ((u16*)Outv)[idx] = f2bf(vv);
            }
        }
    }
}

// ---------------------------------------------------------------------------
// Kernel 5: in-place fp32 LayerNorm over C=512, one wave per row.
// ---------------------------------------------------------------------------
__global__ void ln_kernel(float* __restrict__ out, const float* __restrict__ gamma,
                          const float* __restrict__ beta) {
    int tid = threadIdx.x, w = tid >> 6, l = tid & 63;
    size_t row = (size_t)blockIdx.x * 4 + w;
    float* p = out + row * Cc_ + l * 8;
    f32x4 x0 = *(const f32x4*)p;
    f32x4 x1 = *(const f32x4*)(p + 4);
    float xf[8] = {x0[0], x0[1], x0[2], x0[3], x1[0], x1[1], x1[2], x1[3]};
    float s = 0.f, ss = 0.f;
#pragma unroll
    for (int e = 0; e < 8; e++) {
        s += xf[e];
        ss += xf[e] * xf[e];
    }
#pragma unroll
    for (int off = 32; off > 0; off >>= 1) {
        s += __shfl_xor(s, off);
        ss += __shfl_xor(ss, off);
    }
    float mu = s * (1.f / 512.f);
    float var = ss * (1.f / 512.f) - mu * mu;
    float rs = rsqrtf(var + 1e-5f);
    f32x4 g0 = *(const f32x4*)(gamma + l * 8);
    f32x4 g1 = *(const f32x4*)(gamma + l * 8 + 4);
    f32x4 b0 = *(const f32x4*)(beta + l * 8);
    f32x4 b1 = *(const f32x4*)(beta + l * 8 + 4);
    float gf[8] = {g0[0], g0[1], g0[2], g0[3], g1[0], g1[1], g1[2], g1[3]};
    float bf[8] = {b0[0], b0[1], b0[2], b0[3], b1[0], b1[1], b1[2], b1[3]};
    f32x4 y0, y1;
#pragma unroll
    for (int e = 0; e < 8; e++) {
        float v = (xf[e] - mu) * rs * gf[e] + bf[e];
        if (e < 4) y0[e] = v; else y1[e - 4] = v;
    }
    *(f32x4*)p = y0;
    *(f32x4*)(p + 4) = y1;
}

// ---------------------------------------------------------------------------
extern "C" void kernel_launch(void* const* d_in, const int* in_sizes, int n_in,
                              void* d_out, int out_size, void* d_ws, size_t ws_size,
                              hipStream_t stream) {
    const float* q     = (const float*)d_in[0];
    const float* v     = (const float*)d_in[1];
    const float* W     = (const float*)d_in[2];
    const float* bl    = (const float*)d_in[3];
    const float* gamma = (const float*)d_in[4];
    const float* beta  = (const float*)d_in[5];

    char* ws = (char*)d_ws;
    u16*   WT  = (u16*)ws;                                 // 512*512*2      = 524288
    float* dw  = (float*)(ws + 524288);                    // 128*512*3*4    = 786432
    u16*   pw  = (u16*)(ws + 1310720);                     // 128*512*512*2  = 67108864
    u16*   dT  = (u16*)(ws + 68419584);                    // 128*512*512*2  = 67108864
    float* out = (float*)d_out;
    u16*   qbf = (u16*)d_out;   // first 67 MB of d_out as scratch; dead before GEMM2 writes

    prep_kernel<<<dim3((Bb_ * Nn_) / (4 * ROWS_PER_WAVE)), 256, 0, stream>>>(q, W, bl, qbf, dw);
    wt_kernel<<<dim3(2, 512), 256, 0, stream>>>(W, WT);
    depthT_kernel<<<dim3(8, 8, Bb_), 256, 0, stream>>>(v, dw, dT);

    // GEMM1: pw[b][m][n] = sum_c qbf[b][m][c] * WT[n][c] + b_lin[n+3]   (bf16 out)
    gemm_bt<1, 0><<<dim3(16, Bb_), 256, 0, stream>>>(qbf, WT, pw, bl + 3,
                                                     (long)Nn_ * Cc_, 0L, (long)Nn_ * Nn_);
    // GEMM2: out[b][m][c] = sum_n pw[b][m][n] * depthT[b][c][n]         (fp32 out)
    gemm_bt<0, 1><<<dim3(16, Bb_), 256, 0, stream>>>(pw, dT, out, nullptr,
                                                     (long)Nn_ * Nn_, (long)Cc_ * Nn_, (long)Nn_ * Cc_);

    ln_kernel<<<dim3((Bb_ * Nn_) / 4), 256, 0, stream>>>(out, gamma, beta);
}